// Round 1
// baseline (103.058 us; speedup 1.0000x reference)
//
#include <hip/hip_runtime.h>
#include <cstdint>

#define BB 4
#define NN 1024
#define DD 32
#define NWORDS 16           // NN / 64
#define NEG_INF_F (-1e10f)

// Kernel A: pack each adjacency row into a 1024-bit bitmask (16 x u64) via
// __ballot; the i==0 block of each batch additionally computes the per-batch
// column-max of features (fast-path output for saturated reachability rows).
__global__ __launch_bounds__(256) void pack_kernel(
        const int* __restrict__ edges,
        const float* __restrict__ feat,
        unsigned long long* __restrict__ masks,
        float* __restrict__ colmax) {
    const int row  = blockIdx.x;            // b*NN + i
    const int lane = threadIdx.x & 63;
    const int wave = threadIdx.x >> 6;
    const int* erow = edges + (size_t)row * NN;
#pragma unroll
    for (int s = 0; s < 4; ++s) {
        const int w = wave * 4 + s;
        const int val = erow[w * 64 + lane];
        const unsigned long long bm = __ballot(val != 0);
        if (lane == 0) masks[row * NWORDS + w] = bm;
    }
    const int b = row >> 10;
    const int i = row & (NN - 1);
    if (i == 0) {
        __shared__ float s_red[256];
        const int d  = threadIdx.x & 31;
        const int kc = threadIdx.x >> 5;    // 8 chunks of 128 rows
        const float* fb = feat + (size_t)b * NN * DD;
        float m = -INFINITY;
        for (int kk = 0; kk < 128; ++kk) {
            const int k = kc * 128 + kk;
            m = fmaxf(m, fb[k * DD + d]);
        }
        s_red[threadIdx.x] = m;
        __syncthreads();
        for (int s = 4; s > 0; s >>= 1) {
            if (kc < s)
                s_red[kc * 32 + d] = fmaxf(s_red[kc * 32 + d], s_red[(kc + s) * 32 + d]);
            __syncthreads();
        }
        if (kc == 0) colmax[b * DD + d] = s_red[d];
    }
}

// Kernel B: one block per output row (b,i).
//  Phase 1: w_row = OR_{j: e[i,j]=1} rowmask[j]  (bitset "matmul"), with
//           early exit once a thread's accumulator saturates to all-ones.
//  Phase 2: if w_row is all-ones (overwhelmingly likely for dense random
//           adjacency) copy the precomputed column-max. Otherwise do the
//           exact two-accumulator masked/unmasked max.
__global__ __launch_bounds__(256) void pool_kernel(
        const float* __restrict__ feat,
        const unsigned long long* __restrict__ masks,
        const float* __restrict__ colmax,
        float* __restrict__ out) {
    const int row = blockIdx.x;             // b*NN + i
    const int b   = row >> 10;

    __shared__ unsigned long long s_row[NWORDS];
    __shared__ unsigned long long s_acc[256];
    __shared__ float s_m[256];
    __shared__ float s_u[256];
    __shared__ int   s_allones;

    if (threadIdx.x < NWORDS)
        s_row[threadIdx.x] = masks[row * NWORDS + threadIdx.x];
    __syncthreads();

    // ---- phase 1 ----
    const int w     = threadIdx.x & 15;     // which u64 word of w_row
    const int chunk = threadIdx.x >> 4;     // which 64-j chunk
    const unsigned long long* mb = masks + (size_t)b * NN * NWORDS;
    unsigned long long rw  = s_row[chunk];
    unsigned long long acc = 0ull;
    while (rw) {
        const int jj = __builtin_ctzll(rw);
        rw &= rw - 1;
        acc |= mb[(size_t)(chunk * 64 + jj) * NWORDS + w];
        if (acc == ~0ull) break;            // saturated: no more ORs can change it
    }
    s_acc[threadIdx.x] = acc;
    __syncthreads();
    for (int s = 8; s > 0; s >>= 1) {       // OR-reduce over the 16 chunks
        if (chunk < s)
            s_acc[chunk * 16 + w] |= s_acc[(chunk + s) * 16 + w];
        __syncthreads();
    }
    if (threadIdx.x == 0) {
        unsigned long long a = ~0ull;
        for (int q = 0; q < NWORDS; ++q) a &= s_acc[q];
        s_allones = (a == ~0ull) ? 1 : 0;
    }
    __syncthreads();

    float* orow = out + (size_t)row * DD;
    if (s_allones) {                        // block-uniform fast path
        if (threadIdx.x < DD) orow[threadIdx.x] = colmax[b * DD + threadIdx.x];
        return;
    }

    // ---- phase 2 (general, exact) ----
    const int d  = threadIdx.x & 31;
    const int kc = threadIdx.x >> 5;        // 8 chunks of 128 k
    const float* fb = feat + (size_t)b * NN * DD;
    float mm = -INFINITY, um = -INFINITY;
    for (int kk = 0; kk < 128; ++kk) {
        const int k = kc * 128 + kk;
        const float f = fb[k * DD + d];
        const bool bit = (s_acc[k >> 6] >> (k & 63)) & 1ull;
        if (bit) mm = fmaxf(mm, f); else um = fmaxf(um, f);
    }
    s_m[threadIdx.x] = mm;
    s_u[threadIdx.x] = um;
    __syncthreads();
    for (int s = 4; s > 0; s >>= 1) {
        if (kc < s) {
            s_m[kc * 32 + d] = fmaxf(s_m[kc * 32 + d], s_m[(kc + s) * 32 + d]);
            s_u[kc * 32 + d] = fmaxf(s_u[kc * 32 + d], s_u[(kc + s) * 32 + d]);
        }
        __syncthreads();
    }
    if (kc == 0)
        orow[d] = fmaxf(s_m[d], s_u[d] + NEG_INF_F);
}

extern "C" void kernel_launch(void* const* d_in, const int* in_sizes, int n_in,
                              void* d_out, int out_size, void* d_ws, size_t ws_size,
                              hipStream_t stream) {
    const float* feat  = (const float*)d_in[0];   // [B,N,D] f32
    const int*   edges = (const int*)d_in[1];     // [B,N,N] i32
    float*       out   = (float*)d_out;           // [B,N,D] f32

    unsigned long long* masks  = (unsigned long long*)d_ws;              // 4096*16*8 = 512 KB
    float*              colmax = (float*)((char*)d_ws + (size_t)BB * NN * NWORDS * 8);

    pack_kernel<<<BB * NN, 256, 0, stream>>>(edges, feat, masks, colmax);
    pool_kernel<<<BB * NN, 256, 0, stream>>>(feat, masks, colmax, out);
}

// Round 2
// 92.702 us; speedup vs baseline: 1.1117x; 1.1117x over previous
//
#include <hip/hip_runtime.h>
#include <cstdint>

#define BB 4
#define NN 1024
#define DD 32
#define NWORDS 16           // NN / 64
#define RPB 16              // rows per pool block
#define NEG_INF_F (-1e10f)

// Kernel A: pack each adjacency row into a 1024-bit bitmask (16 x u64) via
// __ballot; the i==0 block of each batch additionally computes the per-batch
// column-max of features (fast-path output for saturated reachability rows).
__global__ __launch_bounds__(256) void pack_kernel(
        const int* __restrict__ edges,
        const float* __restrict__ feat,
        unsigned long long* __restrict__ masks,
        float* __restrict__ colmax) {
    const int row  = blockIdx.x;            // b*NN + i
    const int lane = threadIdx.x & 63;
    const int wave = threadIdx.x >> 6;
    const int* erow = edges + (size_t)row * NN;
#pragma unroll
    for (int s = 0; s < 4; ++s) {
        const int w = wave * 4 + s;
        const int val = erow[w * 64 + lane];
        const unsigned long long bm = __ballot(val != 0);
        if (lane == 0) masks[row * NWORDS + w] = bm;
    }
    const int b = row >> 10;
    const int i = row & (NN - 1);
    if (i == 0) {                            // 4 blocks also compute colmax[b]
        __shared__ float s_red[256];
        const int d  = threadIdx.x & 31;
        const int kc = threadIdx.x >> 5;    // 8 chunks of 128 rows
        const float* fb = feat + (size_t)b * NN * DD;
        float m = -INFINITY;
        for (int kk = 0; kk < 128; ++kk) {
            const int k = kc * 128 + kk;
            m = fmaxf(m, fb[k * DD + d]);
        }
        s_red[threadIdx.x] = m;
        __syncthreads();
        for (int s = 4; s > 0; s >>= 1) {
            if (kc < s)
                s_red[kc * 32 + d] = fmaxf(s_red[kc * 32 + d], s_red[(kc + s) * 32 + d]);
            __syncthreads();
        }
        if (kc == 0) colmax[b * DD + d] = s_red[d];
    }
}

// Kernel B v2: 16 rows per block, 256 threads = 16 rows x 16 words.
// Stage 1: OR masks of each row's neighbors among j in [0,64) from an 8 KB
//          LDS tile (independent loads, no early-exit waitcnt chain).
//          ~32 random ORs saturate a word with prob 1 - 1.5e-8.
// Stage 2 (rare): finish the OR over j in [64,1024) from global masks.
// Stage 3 (prob ~0): exact block-wide masked/unmasked max for rows whose
//          reachability is genuinely not all-ones.
__global__ __launch_bounds__(256) void pool_kernel(
        const float* __restrict__ feat,
        const unsigned long long* __restrict__ masks,
        const float* __restrict__ colmax,
        float* __restrict__ out) {
    const int blk = blockIdx.x;                 // 64 blocks per batch
    const int b   = blk >> 6;
    const int r0  = (blk & 63) * RPB;           // first row (within batch)
    const int t   = threadIdx.x;
    const int il  = t >> 4;                     // local row 0..15
    const int w   = t & 15;                     // mask word 0..15

    __shared__ unsigned long long s_tile[64 * NWORDS];   // 8 KB
    __shared__ unsigned long long s_rw[RPB];
    __shared__ unsigned long long s_acc[RPB * NWORDS];
    __shared__ int   s_nsat[RPB];
    __shared__ int   s_need2[RPB];
    __shared__ float s_m[256];
    __shared__ float s_u[256];

    const unsigned long long* mb = masks + (size_t)b * NN * NWORDS;

    // stage LDS tile: masks of batch rows 0..63 (first 1024 u64, contiguous)
#pragma unroll
    for (int q = 0; q < 4; ++q)
        s_tile[t + q * 256] = mb[t + q * 256];
    if (t < RPB) {
        s_rw[t]    = mb[(size_t)(r0 + t) * NWORDS];  // row's neighbors, j<64
        s_nsat[t]  = 0;
        s_need2[t] = 0;
    }
    __syncthreads();

    // ---- stage 1: OR from LDS tile, independent loads ----
    unsigned long long rw  = s_rw[il];
    unsigned long long acc = 0ull;
    while (rw) {
        const int jj = __builtin_ctzll(rw);
        rw &= rw - 1;
        acc |= s_tile[jj * NWORDS + w];          // no break: keep ILP
    }
    s_acc[il * NWORDS + w] = acc;
    if (acc != ~0ull) atomicAdd(&s_nsat[il], 1);
    __syncthreads();

    // ---- stage 2 (rare): finish OR from global masks ----
    if (s_nsat[il] != 0) {
        unsigned long long a = s_acc[il * NWORDS + w];
        for (int c = 1; c < NWORDS && a != ~0ull; ++c) {
            unsigned long long rwc = mb[(size_t)(r0 + il) * NWORDS + c];
            while (rwc && a != ~0ull) {
                const int jj = __builtin_ctzll(rwc);
                rwc &= rwc - 1;
                a |= mb[(size_t)(c * 64 + jj) * NWORDS + w];
            }
        }
        s_acc[il * NWORDS + w] = a;
        if (a != ~0ull) atomicAdd(&s_need2[il], 1);
    }
    __syncthreads();

    // ---- fast-path output: colmax broadcast (float2 per thread) ----
    const float* cmb = colmax + b * DD;
    float* orow = out + ((size_t)(b * NN + r0) + il) * DD;
    if (s_need2[il] == 0) {
        reinterpret_cast<float2*>(orow)[w] =
            reinterpret_cast<const float2*>(cmb)[w];
    }
    __syncthreads();

    // ---- stage 3 (prob ~0): exact masked max, block-uniform per row ----
    for (int r = 0; r < RPB; ++r) {
        if (s_need2[r] == 0) continue;          // uniform condition
        const int d  = t & 31;
        const int kc = t >> 5;                  // 8 chunks of 128 k
        const float* fb = feat + (size_t)b * NN * DD;
        float mm = -INFINITY, um = -INFINITY;
        for (int kk = 0; kk < 128; ++kk) {
            const int k = kc * 128 + kk;
            const float f = fb[k * DD + d];
            const bool bit = (s_acc[r * NWORDS + (k >> 6)] >> (k & 63)) & 1ull;
            if (bit) mm = fmaxf(mm, f); else um = fmaxf(um, f);
        }
        s_m[t] = mm; s_u[t] = um;
        __syncthreads();
        for (int s = 4; s > 0; s >>= 1) {
            if (kc < s) {
                s_m[kc * 32 + d] = fmaxf(s_m[kc * 32 + d], s_m[(kc + s) * 32 + d]);
                s_u[kc * 32 + d] = fmaxf(s_u[kc * 32 + d], s_u[(kc + s) * 32 + d]);
            }
            __syncthreads();
        }
        if (kc == 0)
            out[((size_t)(b * NN + r0) + r) * DD + d] =
                fmaxf(s_m[d], s_u[d] + NEG_INF_F);
        __syncthreads();
    }
}

extern "C" void kernel_launch(void* const* d_in, const int* in_sizes, int n_in,
                              void* d_out, int out_size, void* d_ws, size_t ws_size,
                              hipStream_t stream) {
    const float* feat  = (const float*)d_in[0];   // [B,N,D] f32
    const int*   edges = (const int*)d_in[1];     // [B,N,N] i32
    float*       out   = (float*)d_out;           // [B,N,D] f32

    unsigned long long* masks  = (unsigned long long*)d_ws;              // 512 KB
    float*              colmax = (float*)((char*)d_ws + (size_t)BB * NN * NWORDS * 8);

    pack_kernel<<<BB * NN, 256, 0, stream>>>(edges, feat, masks, colmax);
    pool_kernel<<<BB * NN / RPB, 256, 0, stream>>>(feat, masks, colmax, out);
}